// Round 2
// baseline (795.992 us; speedup 1.0000x reference)
//
#include <hip/hip_runtime.h>
#include <stdint.h>

typedef short v8s  __attribute__((ext_vector_type(8)));
typedef float v16f __attribute__((ext_vector_type(16)));

#define B_    128
#define C_    64
#define H_    56
#define W_    56
#define HW_   3136
#define NELEM (B_*C_*HW_)          // 25,690,112

// workspace layout (bytes)
#define OFF_K0   0                                  // int8 [B][H][W][C] quantized x (NHWC)
#define OFF_K1   ((size_t)NELEM)                    // int8 x1 (NHWC)
#define OFF_WB   ((size_t)2*NELEM)                  // int8 [2][9][64][64]  (layer, tap, co, ci) signs
#define OFF_PAR  (OFF_WB + 2*9*64*64)               // float: [0..127] qw, [128..255] qb, [256..383] scale=2^p/7
#define OFF_MAX  (OFF_PAR + 384*4)                  // uint32 absmax bits

// ---------------------------------------------------------------- absmax(x)
__global__ void k_absmax(const float* __restrict__ x, unsigned* __restrict__ maxbits) {
    float m = 0.f;
    const int n4 = NELEM / 4;
    for (int i = blockIdx.x * blockDim.x + threadIdx.x; i < n4; i += gridDim.x * blockDim.x) {
        float4 v = ((const float4*)x)[i];
        m = fmaxf(m, fmaxf(fmaxf(fabsf(v.x), fabsf(v.y)), fmaxf(fabsf(v.z), fabsf(v.w))));
    }
    for (int off = 32; off; off >>= 1) m = fmaxf(m, __shfl_down(m, off, 64));
    if ((threadIdx.x & 63) == 0) atomicMax(maxbits, __float_as_uint(m));
}

// ------------------------------------- quantize x -> int8 k in NHWC layout
// faithful f32 chain: k = rint(f32(f32(clip(x,-T,T)/T) * 7))
__global__ void k_quant(const float* __restrict__ x, const unsigned* __restrict__ maxbits,
                        int8_t* __restrict__ k8) {
    __shared__ __align__(16) int8_t tile[W_ * C_];   // [x][c], 3584 B
    const int n = blockIdx.x / H_;
    const int y = blockIdx.x % H_;
    const float T = fminf(fmaxf(__uint_as_float(*maxbits), 1e-10f), 255.0f);
    for (int i = threadIdx.x; i < C_ * 14; i += blockDim.x) {   // 14 float4 per channel row
        int c = i / 14, j = i % 14;
        float4 v = *(const float4*)(x + ((size_t)(n * C_ + c)) * HW_ + y * W_ + j * 4);
        float vv[4] = {v.x, v.y, v.z, v.w};
#pragma unroll
        for (int q = 0; q < 4; q++) {
            float t = fminf(fmaxf(vv[q], -T), T);
            float u = __fdiv_rn(t, T);
            int k = (int)rintf(__fmul_rn(u, 7.0f));
            tile[(j * 4 + q) * C_ + c] = (int8_t)k;
        }
    }
    __syncthreads();
    int4* dst = (int4*)(k8 + ((size_t)(n * H_ + y)) * W_ * C_);
    for (int i = threadIdx.x; i < W_ * C_ / 16; i += blockDim.x)
        dst[i] = ((const int4*)tile)[i];
}

// --------------------------- weight binarization, numpy-pairwise-faithful f32
// 2 blocks (layer) x 64 threads (co); each thread does its channel sequentially,
// mirroring numpy pairwise_sum (576 -> 288 -> 144 -> 72 -> 8-accumulator block).
__device__ __forceinline__ float pw_elem(const float* __restrict__ w, int i, int mode,
                                         float mu, float sig) {
    float xv = w[i];
    if (mode == 0) return xv;
    float d = __fsub_rn(xv, mu);
    if (mode == 1) return __fmul_rn(d, d);
    return fabsf(__fdiv_rn(d, sig));
}

__device__ float pw_block72(const float* __restrict__ w, int base, int mode,
                            float mu, float sig) {
    float r[8];
#pragma unroll
    for (int j = 0; j < 8; j++) r[j] = pw_elem(w, base + j, mode, mu, sig);
    for (int i = 8; i < 72; i += 8)
#pragma unroll
        for (int j = 0; j < 8; j++) r[j] = __fadd_rn(r[j], pw_elem(w, base + i + j, mode, mu, sig));
    float s01 = __fadd_rn(r[0], r[1]), s23 = __fadd_rn(r[2], r[3]);
    float s45 = __fadd_rn(r[4], r[5]), s67 = __fadd_rn(r[6], r[7]);
    return __fadd_rn(__fadd_rn(s01, s23), __fadd_rn(s45, s67));
}

__device__ float pw_sum576(const float* __restrict__ w, int mode, float mu, float sig) {
    float s144a = __fadd_rn(pw_block72(w,   0, mode, mu, sig), pw_block72(w,  72, mode, mu, sig));
    float s144b = __fadd_rn(pw_block72(w, 144, mode, mu, sig), pw_block72(w, 216, mode, mu, sig));
    float s144c = __fadd_rn(pw_block72(w, 288, mode, mu, sig), pw_block72(w, 360, mode, mu, sig));
    float s144d = __fadd_rn(pw_block72(w, 432, mode, mu, sig), pw_block72(w, 504, mode, mu, sig));
    return __fadd_rn(__fadd_rn(s144a, s144b), __fadd_rn(s144c, s144d));
}

__global__ void k_prepw(const float* __restrict__ w1, const float* __restrict__ w2,
                        int8_t* __restrict__ wb, float* __restrict__ par) {
    const int layer = blockIdx.x;
    const int co    = threadIdx.x;
    const float* w = (layer ? w2 : w1) + (size_t)co * 576;

    float mean = __fdiv_rn(pw_sum576(w, 0, 0.f, 1.f), 576.0f);
    float var  = __fdiv_rn(pw_sum576(w, 1, mean, 1.f), 575.0f);
    float sig  = __fsqrt_rn(var);
    float ma   = __fdiv_rn(pw_sum576(w, 2, mean, sig), 576.0f);
    float p    = rintf(log2f(ma));
    par[256 + layer * 64 + co] = __fdiv_rn(exp2f(p), 7.0f);   // scale = 2^p / 7

    for (int i = 0; i < 576; i++) {
        float d = __fsub_rn(w[i], mean);
        int8_t sg = (d > 0.0f) ? (int8_t)1 : ((d < 0.0f) ? (int8_t)-1 : (int8_t)0);
        int ci = i / 9, t = i % 9;
        wb[(((size_t)layer * 9 + t) * 64 + co) * 64 + ci] = sg;
    }
}

// -------------------------------- BN folded affine, quantized, faithful f32
__global__ void k_prepbn(const float* g1, const float* bb1, const float* mm1, const float* vv1,
                         const float* g2, const float* bb2, const float* mm2, const float* vv2,
                         float* __restrict__ par) {
    const int layer = threadIdx.x >> 6;
    const int c = threadIdx.x & 63;
    const float* g  = layer ? g2  : g1;
    const float* be = layer ? bb2 : bb1;
    const float* mu = layer ? mm2 : mm1;
    const float* va = layer ? vv2 : vv1;
    const float stdv = __fsqrt_rn(__fadd_rn(va[c], 1e-5f));
    const float w = __fdiv_rn(g[c], stdv);
    const float b = __fsub_rn(be[c], __fmul_rn(w, mu[c]));
    float aw = fabsf(w), ab = fabsf(b);
    for (int off = 32; off; off >>= 1) {
        aw = fmaxf(aw, __shfl_xor(aw, off, 64));
        ab = fmaxf(ab, __shfl_xor(ab, off, 64));
    }
    const float Tw = fminf(fmaxf(aw, 1e-10f), 255.0f);
    const float Tb = fminf(fmaxf(ab, 1e-10f), 255.0f);
    {   // quantize(w, 3): n = 7
        float vq = __fdiv_rn(fminf(fmaxf(w, -Tw), Tw), Tw);
        float r  = rintf(__fmul_rn(vq, 7.0f));
        float qf = __fadd_rn(vq, __fsub_rn(__fdiv_rn(r, 7.0f), vq));
        par[layer * 64 + c] = __fmul_rn(qf, Tw);
    }
    {   // quantize(b, 12): n = 4095
        float vq = __fdiv_rn(fminf(fmaxf(b, -Tb), Tb), Tb);
        float r  = rintf(__fmul_rn(vq, 4095.0f));
        float qf = __fadd_rn(vq, __fsub_rn(__fdiv_rn(r, 4095.0f), vq));
        par[128 + layer * 64 + c] = __fmul_rn(qf, Tb);
    }
}

// ---------------- int8 (8 bytes) -> bf16x8 fragment; exact for |v| <= 7
__device__ __forceinline__ v8s bf16frag(const int8_t* p) {
    int2 d = *(const int2*)p;
    int dd[2] = {d.x, d.y};
    union { v8s s; unsigned u[4]; } r;
#pragma unroll
    for (int h = 0; h < 2; h++)
#pragma unroll
        for (int pr = 0; pr < 2; pr++) {
            int b0 = (int)(int8_t)(dd[h] >> (pr * 16));
            int b1 = (int)(int8_t)(dd[h] >> (pr * 16 + 8));
            unsigned lo = __float_as_uint((float)b0) >> 16;
            unsigned hi = __float_as_uint((float)b1) >> 16;
            r.u[h * 2 + pr] = lo | (hi << 16);
        }
    return r.s;
}

// ------------------------------------------------ fused conv + BN + residual
// grid: B*28 blocks; block = (n, rows y0,y0+1) -> M = 112 positions, N = 64 co
// bf16 MFMA 32x32x16 (HW-verified layout); S is exact (ints < 2^24 in f32 acc)
template <int LAYER>
__global__ __launch_bounds__(256) void k_conv(const int8_t* __restrict__ kin,
                                              const int8_t* __restrict__ wb,
                                              const float* __restrict__ par,
                                              int8_t* __restrict__ kout,
                                              float* __restrict__ fout) {
    __shared__ __align__(16) int8_t halo[4 * 58 * 64];   // 14848 B
    __shared__ __align__(16) int8_t wsm[9 * 64 * 64];    // 36864 B (reused by epilogue stage)
    const int n  = blockIdx.x / 28;
    const int y0 = (blockIdx.x % 28) * 2;
    const int tid = threadIdx.x;

    // stage halo (zero-padded), 16B units
    for (int u = tid; u < 928; u += 256) {
        int r = u / 232, rem = u % 232;
        int cp = rem / 4, part = rem % 4;
        int y = y0 - 1 + r, xg = cp - 1;
        int4 val = {0, 0, 0, 0};
        if (y >= 0 && y < 56 && xg >= 0 && xg < 56)
            val = *(const int4*)(kin + (((size_t)(n * 56 + y)) * 56 + xg) * 64 + part * 16);
        *(int4*)(halo + u * 16) = val;
    }
    // stage this layer's binary weights
    const int8_t* wsrc = wb + (size_t)(LAYER - 1) * 9 * 64 * 64;
    for (int u = tid; u < 2304; u += 256)
        *(int4*)(wsm + u * 16) = *(const int4*)(wsrc + u * 16);
    __syncthreads();

    const int wv = tid >> 6, lane = tid & 63;
    const int mbase = wv * 32;
    const int ml = lane & 31;
    const int khalf = lane >> 5;
    const int m = mbase + ml;
    const int m_eff = (m < 112) ? m : 111;
    const int rm = m_eff / 56, cm = m_eff % 56;

    v16f acc0, acc1;
#pragma unroll
    for (int i = 0; i < 16; i++) { acc0[i] = 0.0f; acc1[i] = 0.0f; }

#pragma unroll
    for (int s = 0; s < 9; s++) {
        const int ky = s / 3, kx = s % 3;
        const int arow  = ((rm + ky) * 58 + (cm + kx)) * 64;
        const int brow0 = (s * 64 + ml) * 64;
        const int brow1 = (s * 64 + 32 + ml) * 64;
#pragma unroll
        for (int kb = 0; kb < 4; kb++) {
            const int ko = kb * 16 + khalf * 8;
            v8s af = bf16frag(halo + arow  + ko);
            v8s b0 = bf16frag(wsm  + brow0 + ko);
            v8s b1 = bf16frag(wsm  + brow1 + ko);
            acc0 = __builtin_amdgcn_mfma_f32_32x32x16_bf16(af, b0, acc0, 0, 0, 0);
            acc1 = __builtin_amdgcn_mfma_f32_32x32x16_bf16(af, b1, acc1, 0, 0, 0);
        }
    }
    __syncthreads();   // all MFMA reads of wsm done; safe to reuse as out stage

    const float* qw = par + (LAYER - 1) * 64;
    const float* qb = par + 128 + (LAYER - 1) * 64;
    const float* sc = par + 256 + (LAYER - 1) * 64;
#pragma unroll
    for (int t = 0; t < 2; t++) {
        const int co = ml + t * 32;
        const float qwf = qw[co], qbf = qb[co], scf = sc[co];
#pragma unroll
        for (int r = 0; r < 16; r++) {
            const int mrow = mbase + (r & 3) + 8 * (r >> 2) + 4 * khalf;
            if (mrow >= 112) continue;
            const float Sf = t ? acc1[r] : acc0[r];    // exact integer
            // faithful f32: aq = qfn(conv/576, 10) * 576
            float convf = __fmul_rn(Sf, scf);          // = S * 2^p / 7
            float xb = __fdiv_rn(convf, 576.0f);
            float rr = rintf(__fmul_rn(xb, 1023.0f));
            float q1 = __fdiv_rn(rr, 1023.0f);
            float y1 = __fadd_rn(xb, __fsub_rn(q1, xb));
            float aq = __fmul_rn(y1, 576.0f);
            const int rloc = mrow / 56, cloc = mrow % 56;
            float kcf = (float)halo[((rloc + 1) * 58 + (cloc + 1)) * 64 + co];
            float xqv = __fdiv_rn(kcf, 7.0f);
            float val = __fadd_rn(__fadd_rn(__fmul_rn(aq, qwf), qbf), xqv);
            val = fminf(fmaxf(val, -1.0f), 1.0f);      // hardtanh
            if (LAYER == 1) {
                // T1 == 1.0 (saturation certain): k2 = rint(out * 7)
                int k2 = (int)rintf(__fmul_rn(val, 7.0f));
                wsm[mrow * 64 + co] = (int8_t)k2;
            } else {
                *(float*)&wsm[((size_t)co * 112 + mrow) * 4] = val;
            }
        }
    }
    __syncthreads();

    const size_t posbase = (size_t)n * HW_ + (size_t)y0 * 56;
    if (LAYER == 1) {
        int4* dst = (int4*)(kout + posbase * 64);
        for (int u = tid; u < 448; u += 256) dst[u] = ((const int4*)wsm)[u];
    } else {
        for (int u = tid; u < 1792; u += 256) {
            int co = u / 28, q = u % 28;
            float4 v = *((const float4*)wsm + co * 28 + q);
            *(float4*)(fout + ((size_t)(n * 64 + co)) * HW_ + (size_t)y0 * 56 + q * 4) = v;
        }
    }
}

// ----------------------------------------------------------------- launcher
extern "C" void kernel_launch(void* const* d_in, const int* in_sizes, int n_in,
                              void* d_out, int out_size, void* d_ws, size_t ws_size,
                              hipStream_t stream) {
    const float* x  = (const float*)d_in[0];
    const float* w1 = (const float*)d_in[1];
    const float* w2 = (const float*)d_in[2];
    const float* g1 = (const float*)d_in[3];
    const float* b1 = (const float*)d_in[4];
    const float* m1 = (const float*)d_in[5];
    const float* v1 = (const float*)d_in[6];
    const float* g2 = (const float*)d_in[7];
    const float* b2 = (const float*)d_in[8];
    const float* m2 = (const float*)d_in[9];
    const float* v2 = (const float*)d_in[10];

    char* ws = (char*)d_ws;
    int8_t*  k0  = (int8_t*)(ws + OFF_K0);
    int8_t*  k1  = (int8_t*)(ws + OFF_K1);
    int8_t*  wbp = (int8_t*)(ws + OFF_WB);
    float*   par = (float*)(ws + OFF_PAR);
    unsigned* mx = (unsigned*)(ws + OFF_MAX);

    hipMemsetAsync(mx, 0, 4, stream);
    k_absmax<<<4096, 256, 0, stream>>>(x, mx);
    k_quant<<<B_ * H_, 256, 0, stream>>>(x, mx, k0);
    k_prepw<<<2, 64, 0, stream>>>(w1, w2, wbp, par);
    k_prepbn<<<1, 128, 0, stream>>>(g1, b1, m1, v1, g2, b2, m2, v2, par);
    k_conv<1><<<B_ * 28, 256, 0, stream>>>(k0, wbp, par, k1, nullptr);
    k_conv<2><<<B_ * 28, 256, 0, stream>>>(k1, wbp, par, nullptr, (float*)d_out);
}

// Round 3
// 350.014 us; speedup vs baseline: 2.2742x; 2.2742x over previous
//
#include <hip/hip_runtime.h>
#include <stdint.h>

typedef int v4i   __attribute__((ext_vector_type(4)));
typedef int v16i  __attribute__((ext_vector_type(16)));

#define B_    128
#define C_    64
#define H_    56
#define W_    56
#define HW_   3136
#define NELEM (B_*C_*HW_)          // 25,690,112

// workspace layout (bytes)
#define OFF_K0   0                                  // int8 [B][H][W][C] quantized x (NHWC)
#define OFF_K1   ((size_t)NELEM)                    // int8 x1 (NHWC)
#define OFF_WB   ((size_t)2*NELEM)                  // int8 [2][9][64][64]  (layer, tap, co, ci) signs
#define OFF_PAR  (OFF_WB + 2*9*64*64)               // float: [0..127] qw, [128..255] qb, [256..383] scale=2^p/7
#define OFF_MAX  (OFF_PAR + 384*4)                  // uint32 absmax bits

// ---------------------------------------------------------------- absmax(x)
// block-level reduce, ONE atomic per block (round-2 had 16K same-address atomics)
__global__ void k_absmax(const float* __restrict__ x, unsigned* __restrict__ maxbits) {
    __shared__ float smax[4];
    float m = 0.f;
    const int n4 = NELEM / 4;
    for (int i = blockIdx.x * blockDim.x + threadIdx.x; i < n4; i += gridDim.x * blockDim.x) {
        float4 v = ((const float4*)x)[i];
        m = fmaxf(m, fmaxf(fmaxf(fabsf(v.x), fabsf(v.y)), fmaxf(fabsf(v.z), fabsf(v.w))));
    }
    for (int off = 32; off; off >>= 1) m = fmaxf(m, __shfl_down(m, off, 64));
    if ((threadIdx.x & 63) == 0) smax[threadIdx.x >> 6] = m;
    __syncthreads();
    if (threadIdx.x == 0) {
        float mm = fmaxf(fmaxf(smax[0], smax[1]), fmaxf(smax[2], smax[3]));
        atomicMax(maxbits, __float_as_uint(mm));   // nonneg floats: uint order == float order
    }
}

// ------------------------------------- quantize x -> int8 k in NHWC layout
// faithful f32 chain: k = rint(f32(f32(clip(x,-T,T)/T) * 7))
__global__ void k_quant(const float* __restrict__ x, const unsigned* __restrict__ maxbits,
                        int8_t* __restrict__ k8) {
    __shared__ __align__(16) int8_t tile[W_ * C_];   // [x][c], 3584 B
    const int n = blockIdx.x / H_;
    const int y = blockIdx.x % H_;
    const float T = fminf(fmaxf(__uint_as_float(*maxbits), 1e-10f), 255.0f);
    for (int i = threadIdx.x; i < C_ * 14; i += blockDim.x) {   // 14 float4 per channel row
        int c = i / 14, j = i % 14;
        float4 v = *(const float4*)(x + ((size_t)(n * C_ + c)) * HW_ + y * W_ + j * 4);
        float vv[4] = {v.x, v.y, v.z, v.w};
#pragma unroll
        for (int q = 0; q < 4; q++) {
            float t = fminf(fmaxf(vv[q], -T), T);
            float u = __fdiv_rn(t, T);
            int k = (int)rintf(__fmul_rn(u, 7.0f));
            tile[(j * 4 + q) * C_ + c] = (int8_t)k;
        }
    }
    __syncthreads();
    int4* dst = (int4*)(k8 + ((size_t)(n * H_ + y)) * W_ * C_);
    for (int i = threadIdx.x; i < W_ * C_ / 16; i += blockDim.x)
        dst[i] = ((const int4*)tile)[i];
}

// --------------------------- weight binarization, numpy-pairwise-faithful f32
// 128 blocks x 64 threads: block = (layer, co). Lane = (block-of-72 [5:3], accum slot [2:0]).
// Butterfly xor-combine reproduces numpy's pairwise tree bitwise (IEEE add is
// commutative; every level only swaps operand order, which is bitwise-neutral).
__device__ __forceinline__ float pw_reduce64(float r) {
    r = __fadd_rn(r, __shfl_xor(r, 1, 64));    // r0+r1 within 8-acc block
    r = __fadd_rn(r, __shfl_xor(r, 2, 64));    // (r0+r1)+(r2+r3)
    r = __fadd_rn(r, __shfl_xor(r, 4, 64));    // block72 sum
    r = __fadd_rn(r, __shfl_xor(r, 8, 64));    // 72+72 = 144
    r = __fadd_rn(r, __shfl_xor(r, 16, 64));   // 144+144 = 288
    r = __fadd_rn(r, __shfl_xor(r, 32, 64));   // 288+288 = 576
    return r;
}

__global__ void k_prepw(const float* __restrict__ w1, const float* __restrict__ w2,
                        int8_t* __restrict__ wb, float* __restrict__ par) {
    const int layer = blockIdx.x >> 6;
    const int co    = blockIdx.x & 63;
    const float* w = (layer ? w2 : w1) + (size_t)co * 576;
    const int lane = threadIdx.x;
    const int base = (lane >> 3) * 72 + (lane & 7);   // my accumulator's first element

    float v[9];
#pragma unroll
    for (int i = 0; i < 9; i++) v[i] = w[base + 8 * i];

    // pass 1: mean
    float s = v[0];
#pragma unroll
    for (int i = 1; i < 9; i++) s = __fadd_rn(s, v[i]);
    const float mean = __fdiv_rn(pw_reduce64(s), 576.0f);

    // pass 2: var (ddof=1)
    float d0 = __fsub_rn(v[0], mean);
    float sq = __fmul_rn(d0, d0);
#pragma unroll
    for (int i = 1; i < 9; i++) {
        float d = __fsub_rn(v[i], mean);
        sq = __fadd_rn(sq, __fmul_rn(d, d));
    }
    const float sig = __fsqrt_rn(__fdiv_rn(pw_reduce64(sq), 575.0f));

    // pass 3: mean |bw|
    float sa = fabsf(__fdiv_rn(__fsub_rn(v[0], mean), sig));
#pragma unroll
    for (int i = 1; i < 9; i++)
        sa = __fadd_rn(sa, fabsf(__fdiv_rn(__fsub_rn(v[i], mean), sig)));
    const float ma = __fdiv_rn(pw_reduce64(sa), 576.0f);
    const float p  = rintf(log2f(ma));
    if (lane == 0) par[256 + layer * 64 + co] = __fdiv_rn(exp2f(p), 7.0f);  // scale = 2^p/7

    // signs -> wb[(layer*9 + t)*64 + co][ci]
#pragma unroll
    for (int i = 0; i < 9; i++) {
        int ig = base + 8 * i;
        float d = __fsub_rn(v[i], mean);
        int8_t sg = (d > 0.0f) ? (int8_t)1 : ((d < 0.0f) ? (int8_t)-1 : (int8_t)0);
        int ci = ig / 9, t = ig % 9;
        wb[(((size_t)layer * 9 + t) * 64 + co) * 64 + ci] = sg;
    }
}

// -------------------------------- BN folded affine, quantized, faithful f32
__global__ void k_prepbn(const float* g1, const float* bb1, const float* mm1, const float* vv1,
                         const float* g2, const float* bb2, const float* mm2, const float* vv2,
                         float* __restrict__ par) {
    const int layer = threadIdx.x >> 6;
    const int c = threadIdx.x & 63;
    const float* g  = layer ? g2  : g1;
    const float* be = layer ? bb2 : bb1;
    const float* mu = layer ? mm2 : mm1;
    const float* va = layer ? vv2 : vv1;
    const float stdv = __fsqrt_rn(__fadd_rn(va[c], 1e-5f));
    const float w = __fdiv_rn(g[c], stdv);
    const float b = __fsub_rn(be[c], __fmul_rn(w, mu[c]));
    float aw = fabsf(w), ab = fabsf(b);
    for (int off = 32; off; off >>= 1) {
        aw = fmaxf(aw, __shfl_xor(aw, off, 64));
        ab = fmaxf(ab, __shfl_xor(ab, off, 64));
    }
    const float Tw = fminf(fmaxf(aw, 1e-10f), 255.0f);
    const float Tb = fminf(fmaxf(ab, 1e-10f), 255.0f);
    {   // quantize(w, 3): n = 7
        float vq = __fdiv_rn(fminf(fmaxf(w, -Tw), Tw), Tw);
        float r  = rintf(__fmul_rn(vq, 7.0f));
        float qf = __fadd_rn(vq, __fsub_rn(__fdiv_rn(r, 7.0f), vq));
        par[layer * 64 + c] = __fmul_rn(qf, Tw);
    }
    {   // quantize(b, 12): n = 4095
        float vq = __fdiv_rn(fminf(fmaxf(b, -Tb), Tb), Tb);
        float r  = rintf(__fmul_rn(vq, 4095.0f));
        float qf = __fadd_rn(vq, __fsub_rn(__fdiv_rn(r, 4095.0f), vq));
        par[128 + layer * 64 + c] = __fmul_rn(qf, Tb);
    }
}

// ------------------------------------------------ fused conv + BN + residual
// grid: B*28 blocks; block = (n, rows y0,y0+1) -> M = 112 positions, N = 64 co
// i8 MFMA 32x32x32: exact int32 S; A/B fragment = K-doubled analog of the
// bitwise-verified bf16 32x32x16 layout (lane m + 32*khalf holds k=khalf*16+[0..15]).
template <int LAYER>
__global__ __launch_bounds__(256) void k_conv(const int8_t* __restrict__ kin,
                                              const int8_t* __restrict__ wb,
                                              const float* __restrict__ par,
                                              int8_t* __restrict__ kout,
                                              float* __restrict__ fout) {
    __shared__ __align__(16) int8_t halo[4 * 58 * 64];   // 14848 B
    __shared__ __align__(16) int8_t wsm[9 * 64 * 64];    // 36864 B (reused by epilogue stage)
    const int n  = blockIdx.x / 28;
    const int y0 = (blockIdx.x % 28) * 2;
    const int tid = threadIdx.x;

    // stage halo (zero-padded), 16B units
    for (int u = tid; u < 928; u += 256) {
        int r = u / 232, rem = u % 232;
        int cp = rem / 4, part = rem % 4;
        int y = y0 - 1 + r, xg = cp - 1;
        int4 val = {0, 0, 0, 0};
        if (y >= 0 && y < 56 && xg >= 0 && xg < 56)
            val = *(const int4*)(kin + (((size_t)(n * 56 + y)) * 56 + xg) * 64 + part * 16);
        *(int4*)(halo + u * 16) = val;
    }
    // stage this layer's binary weights
    const int8_t* wsrc = wb + (size_t)(LAYER - 1) * 9 * 64 * 64;
    for (int u = tid; u < 2304; u += 256)
        *(int4*)(wsm + u * 16) = *(const int4*)(wsrc + u * 16);
    __syncthreads();

    const int wv = tid >> 6, lane = tid & 63;
    const int mbase = wv * 32;
    const int ml = lane & 31;
    const int khalf = lane >> 5;
    const int m = mbase + ml;
    const int m_eff = (m < 112) ? m : 111;
    const int rm = m_eff / 56, cm = m_eff % 56;

    v16i acc0, acc1;
#pragma unroll
    for (int i = 0; i < 16; i++) { acc0[i] = 0; acc1[i] = 0; }

#pragma unroll
    for (int s = 0; s < 9; s++) {
        const int ky = s / 3, kx = s % 3;
        const int abase  = ((rm + ky) * 58 + (cm + kx)) * 64 + khalf * 16;
        const int bbase0 = (s * 64 + ml) * 64 + khalf * 16;
        const int bbase1 = (s * 64 + 32 + ml) * 64 + khalf * 16;
#pragma unroll
        for (int kb = 0; kb < 2; kb++) {
            v4i a  = *(const v4i*)(halo + abase  + kb * 32);
            v4i b0 = *(const v4i*)(wsm  + bbase0 + kb * 32);
            v4i b1 = *(const v4i*)(wsm  + bbase1 + kb * 32);
            acc0 = __builtin_amdgcn_mfma_i32_32x32x32_i8(a, b0, acc0, 0, 0, 0);
            acc1 = __builtin_amdgcn_mfma_i32_32x32x32_i8(a, b1, acc1, 0, 0, 0);
        }
    }
    __syncthreads();   // all MFMA reads of wsm done; safe to reuse as out stage

    const float* qw = par + (LAYER - 1) * 64;
    const float* qb = par + 128 + (LAYER - 1) * 64;
    const float* sc = par + 256 + (LAYER - 1) * 64;
#pragma unroll
    for (int t = 0; t < 2; t++) {
        const int co = ml + t * 32;
        const float qwf = qw[co], qbf = qb[co], scf = sc[co];
#pragma unroll
        for (int r = 0; r < 16; r++) {
            const int mrow = mbase + (r & 3) + 8 * (r >> 2) + 4 * khalf;
            if (mrow >= 112) continue;
            const float Sf = (float)(t ? acc1[r] : acc0[r]);   // |S| <= 4032: exact
            // faithful f32: aq = qfn(conv/576, 10) * 576   (byte-identical to round-2 pass)
            float convf = __fmul_rn(Sf, scf);                  // = S * 2^p / 7
            float xb = __fdiv_rn(convf, 576.0f);
            float rr = rintf(__fmul_rn(xb, 1023.0f));
            float q1 = __fdiv_rn(rr, 1023.0f);
            float y1 = __fadd_rn(xb, __fsub_rn(q1, xb));
            float aq = __fmul_rn(y1, 576.0f);
            const int rloc = mrow / 56, cloc = mrow % 56;
            float kcf = (float)halo[((rloc + 1) * 58 + (cloc + 1)) * 64 + co];
            float xqv = __fdiv_rn(kcf, 7.0f);
            float val = __fadd_rn(__fadd_rn(__fmul_rn(aq, qwf), qbf), xqv);
            val = fminf(fmaxf(val, -1.0f), 1.0f);              // hardtanh
            if (LAYER == 1) {
                // T1 == 1.0 (saturation certain): k2 = rint(out * 7)
                int k2 = (int)rintf(__fmul_rn(val, 7.0f));
                wsm[mrow * 64 + co] = (int8_t)k2;
            } else {
                *(float*)&wsm[((size_t)co * 112 + mrow) * 4] = val;
            }
        }
    }
    __syncthreads();

    const size_t posbase = (size_t)n * HW_ + (size_t)y0 * 56;
    if (LAYER == 1) {
        int4* dst = (int4*)(kout + posbase * 64);
        for (int u = tid; u < 448; u += 256) dst[u] = ((const int4*)wsm)[u];
    } else {
        for (int u = tid; u < 1792; u += 256) {
            int co = u / 28, q = u % 28;
            float4 v = *((const float4*)wsm + co * 28 + q);
            *(float4*)(fout + ((size_t)(n * 64 + co)) * HW_ + (size_t)y0 * 56 + q * 4) = v;
        }
    }
}

// ----------------------------------------------------------------- launcher
extern "C" void kernel_launch(void* const* d_in, const int* in_sizes, int n_in,
                              void* d_out, int out_size, void* d_ws, size_t ws_size,
                              hipStream_t stream) {
    const float* x  = (const float*)d_in[0];
    const float* w1 = (const float*)d_in[1];
    const float* w2 = (const float*)d_in[2];
    const float* g1 = (const float*)d_in[3];
    const float* b1 = (const float*)d_in[4];
    const float* m1 = (const float*)d_in[5];
    const float* v1 = (const float*)d_in[6];
    const float* g2 = (const float*)d_in[7];
    const float* b2 = (const float*)d_in[8];
    const float* m2 = (const float*)d_in[9];
    const float* v2 = (const float*)d_in[10];

    char* ws = (char*)d_ws;
    int8_t*  k0  = (int8_t*)(ws + OFF_K0);
    int8_t*  k1  = (int8_t*)(ws + OFF_K1);
    int8_t*  wbp = (int8_t*)(ws + OFF_WB);
    float*   par = (float*)(ws + OFF_PAR);
    unsigned* mx = (unsigned*)(ws + OFF_MAX);

    hipMemsetAsync(mx, 0, 4, stream);
    k_absmax<<<1024, 256, 0, stream>>>(x, mx);
    k_quant<<<B_ * H_, 256, 0, stream>>>(x, mx, k0);
    k_prepw<<<128, 64, 0, stream>>>(w1, w2, wbp, par);
    k_prepbn<<<1, 128, 0, stream>>>(g1, b1, m1, v1, g2, b2, m2, v2, par);
    k_conv<1><<<B_ * 28, 256, 0, stream>>>(k0, wbp, par, k1, nullptr);
    k_conv<2><<<B_ * 28, 256, 0, stream>>>(k1, wbp, par, nullptr, (float*)d_out);
}